// Round 1
// baseline (17287.590 us; speedup 1.0000x reference)
//
#include <hip/hip_runtime.h>

#define LSTM_B   4096
#define LSTM_H   1024
#define LSTM_IN  512
#define LSTM_OUT 512

typedef unsigned long long u64;
typedef unsigned int u32;

__device__ __forceinline__ u64 aload(u64* p) {
  return __hip_atomic_load(p, __ATOMIC_RELAXED, __HIP_MEMORY_SCOPE_AGENT);
}
__device__ __forceinline__ void astore(u64* p, u64 v) {
  __hip_atomic_store(p, v, __ATOMIC_RELAXED, __HIP_MEMORY_SCOPE_AGENT);
}
__device__ __forceinline__ u64 packft(float f, u32 tag) {
  return ((u64)tag << 32) | (u64)__float_as_uint(f);
}
__device__ __forceinline__ float dot4f(float4 a, float4 b) {
  return fmaf(a.x, b.x, fmaf(a.y, b.y, fmaf(a.z, b.z, a.w * b.w)));
}
__device__ __forceinline__ float sigf(float x) { return 1.0f / (1.0f + expf(-x)); }

// ---------------- transpose fc_w [512,1024] -> fcwT [1024,512] ----------------
__global__ void k_transpose(const float* __restrict__ w, float* __restrict__ wT) {
  int idx = blockIdx.x * 256 + threadIdx.x;   // 512*1024 total
  int k = idx >> 9;
  int o = idx & 511;
  wT[idx] = w[o * 1024 + k];
}

// ---------------- persistent recurrent kernel ----------------
// 256 blocks (1/CU) x 1024 threads. Block bx owns hidden indices 4bx..4bx+3.
// Wave w (0..15) -> gate g=w>>2, local hid j=w&3, row R=g*1024+4bx+j.
// Lane l covers k in {q*256+4l..+3 : q}. Weights stay in VGPRs for all 4096 steps.
// h broadcast: packed (tag<<32)|fp32 written once per slot via agent-scope atomics.
__global__ __launch_bounds__(1024) void k_recur(
    const float* __restrict__ x,
    const float* __restrict__ Whh0, const float* __restrict__ Wih0,
    const float* __restrict__ bih0, const float* __restrict__ bhh0,
    const float* __restrict__ Wih1, const float* __restrict__ Whh1,
    const float* __restrict__ bih1, const float* __restrict__ bhh1,
    const float* __restrict__ h0in, const float* __restrict__ c0in,
    u64* __restrict__ h0buf, u64* __restrict__ h1buf)
{
  __shared__ float h0s[LSTM_H], h1s[LSTM_H], xs[LSTM_IN];
  __shared__ float s_hh0[16], s_ih0[16], s_ih1[16], s_hh1[16];
  __shared__ float b0s[16], b1s[16];

  const int tid = threadIdx.x;
  const int w = tid >> 6, l = tid & 63;
  const int bx = blockIdx.x;
  const int g = w >> 2, j = w & 3;
  const int R = g * 1024 + 4 * bx + j;

  // weights -> registers (56 fp32/thread), lane-l chunks are 16B aligned+coalesced
  float4 wa[4], wb[4], wc[4];
#pragma unroll
  for (int q = 0; q < 4; ++q) {
    wa[q] = *(const float4*)&Whh0[(size_t)R * 1024 + q * 256 + 4 * l];
    wb[q] = *(const float4*)&Wih1[(size_t)R * 1024 + q * 256 + 4 * l];
    wc[q] = *(const float4*)&Whh1[(size_t)R * 1024 + q * 256 + 4 * l];
  }
  float4 wx0 = *(const float4*)&Wih0[(size_t)R * 512 + 4 * l];
  float4 wx1 = *(const float4*)&Wih0[(size_t)R * 512 + 256 + 4 * l];

  if (tid < 16) {
    int gg = tid >> 2, jj = tid & 3;
    int RR = gg * 1024 + 4 * bx + jj;
    b0s[tid] = bih0[RR] + bhh0[RR];
    b1s[tid] = bih1[RR] + bhh1[RR];
  }

  // cell states: thread j (0..3) owns layer1 hid 4bx+j; thread 64+j owns layer0
  float c0st = 0.f, c1st = 0.f;
  if (tid >= 64 && tid < 68) c0st = c0in[4 * bx + (tid - 64)];
  if (tid < 4)               c1st = c0in[1024 + 4 * bx + tid];

  // ---- prologue: layer0 step 0 from h0_init, x[0]; seed h1buf[0] with h1_init
  h0s[tid] = h0in[tid];
  if (tid < 512) xs[tid] = x[tid];
  __syncthreads();
  {
    float sh = 0.f, sx = 0.f;
#pragma unroll
    for (int q = 0; q < 4; ++q) sh += dot4f(wa[q], *(const float4*)&h0s[q * 256 + 4 * l]);
    sx += dot4f(wx0, *(const float4*)&xs[4 * l]);
    sx += dot4f(wx1, *(const float4*)&xs[256 + 4 * l]);
#pragma unroll
    for (int m = 1; m < 64; m <<= 1) {
      sh += __shfl_xor(sh, m, 64);
      sx += __shfl_xor(sx, m, 64);
    }
    if (l == 0) { s_hh0[w] = sh; s_ih0[w] = sx; }
  }
  __syncthreads();
  if (tid >= 64 && tid < 68) {
    int jj = tid - 64, hd = 4 * bx + jj;
    float gi = s_ih0[jj]      + s_hh0[jj]      + b0s[jj];
    float gf = s_ih0[4 + jj]  + s_hh0[4 + jj]  + b0s[4 + jj];
    float gc = s_ih0[8 + jj]  + s_hh0[8 + jj]  + b0s[8 + jj];
    float go = s_ih0[12 + jj] + s_hh0[12 + jj] + b0s[12 + jj];
    c0st = sigf(gf) * c0st + sigf(gi) * tanhf(gc);
    float h0n = sigf(go) * tanhf(c0st);
    astore(&h0buf[hd], packft(h0n, 0u));
  }
  if (tid < 4) {
    int hd = 4 * bx + tid;
    astore(&h1buf[hd], packft(h0in[1024 + hd], 0u));
  }

  // ---- main loop: phase t computes layer1(t) and layer0(t+1)
#pragma unroll 1
  for (int t = 0; t < LSTM_B; ++t) {
    if (t + 1 < LSTM_B && tid < 512) xs[tid] = x[(size_t)(t + 1) * 512 + tid];
    {
      u64* p0 = &h0buf[(size_t)t * 1024 + tid];
      u64* p1 = &h1buf[(size_t)t * 1024 + tid];
      u64 v0 = aload(p0);
      u64 v1 = aload(p1);
      while ((u32)(v0 >> 32) != (u32)t) { __builtin_amdgcn_s_sleep(1); v0 = aload(p0); }
      while ((u32)(v1 >> 32) != (u32)t) { __builtin_amdgcn_s_sleep(1); v1 = aload(p1); }
      h0s[tid] = __uint_as_float((u32)v0);
      h1s[tid] = __uint_as_float((u32)v1);
    }
    __syncthreads();

    float shh0 = 0.f, six0 = 0.f, sih1 = 0.f, shh1 = 0.f;
#pragma unroll
    for (int q = 0; q < 4; ++q) {
      float4 h0q = *(const float4*)&h0s[q * 256 + 4 * l];
      float4 h1q = *(const float4*)&h1s[q * 256 + 4 * l];
      shh0 += dot4f(wa[q], h0q);
      sih1 += dot4f(wb[q], h0q);
      shh1 += dot4f(wc[q], h1q);
    }
    six0 = dot4f(wx0, *(const float4*)&xs[4 * l]) +
           dot4f(wx1, *(const float4*)&xs[256 + 4 * l]);
#pragma unroll
    for (int m = 1; m < 64; m <<= 1) {
      shh0 += __shfl_xor(shh0, m, 64);
      six0 += __shfl_xor(six0, m, 64);
      sih1 += __shfl_xor(sih1, m, 64);
      shh1 += __shfl_xor(shh1, m, 64);
    }
    if (l == 0) { s_hh0[w] = shh0; s_ih0[w] = six0; s_ih1[w] = sih1; s_hh1[w] = shh1; }
    __syncthreads();

    if (tid < 4) {  // layer1 step t
      int jj = tid, hd = 4 * bx + jj;
      float gi = s_ih1[jj]      + s_hh1[jj]      + b1s[jj];
      float gf = s_ih1[4 + jj]  + s_hh1[4 + jj]  + b1s[4 + jj];
      float gc = s_ih1[8 + jj]  + s_hh1[8 + jj]  + b1s[8 + jj];
      float go = s_ih1[12 + jj] + s_hh1[12 + jj] + b1s[12 + jj];
      c1st = sigf(gf) * c1st + sigf(gi) * tanhf(gc);
      float h1n = sigf(go) * tanhf(c1st);
      astore(&h1buf[(size_t)(t + 1) * 1024 + hd], packft(h1n, (u32)(t + 1)));
    }
    if (t + 1 < LSTM_B && tid >= 64 && tid < 68) {  // layer0 step t+1
      int jj = tid - 64, hd = 4 * bx + jj;
      float gi = s_ih0[jj]      + s_hh0[jj]      + b0s[jj];
      float gf = s_ih0[4 + jj]  + s_hh0[4 + jj]  + b0s[4 + jj];
      float gc = s_ih0[8 + jj]  + s_hh0[8 + jj]  + b0s[8 + jj];
      float go = s_ih0[12 + jj] + s_hh0[12 + jj] + b0s[12 + jj];
      c0st = sigf(gf) * c0st + sigf(gi) * tanhf(gc);
      float h0n = sigf(go) * tanhf(c0st);
      astore(&h0buf[(size_t)(t + 1) * 1024 + hd], packft(h0n, (u32)(t + 1)));
    }
  }
}

// ---------------- FC + softmax: 16 timesteps per block ----------------
__global__ __launch_bounds__(256) void k_fc(u64* __restrict__ h1buf,
                                            const float* __restrict__ fcwT,
                                            const float* __restrict__ fcb,
                                            float* __restrict__ out) {
  __shared__ float smem[16 * 1024];
  const int tid = threadIdx.x;
  const int t0 = blockIdx.x * 16;

  for (int i = 0; i < 64; ++i) {
    int e = tid + 256 * i;
    int tt = e >> 10, k = e & 1023;
    u64 v = aload(&h1buf[(size_t)(t0 + tt + 1) * 1024 + k]);
    smem[e] = __uint_as_float((u32)v);
  }
  __syncthreads();

  float acc0[16], acc1[16];
#pragma unroll
  for (int tt = 0; tt < 16; ++tt) { acc0[tt] = 0.f; acc1[tt] = 0.f; }

  for (int k0 = 0; k0 < 1024; k0 += 4) {
    float4 w0v, w1v;
    w0v.x = fcwT[(k0 + 0) * 512 + tid];       w1v.x = fcwT[(k0 + 0) * 512 + 256 + tid];
    w0v.y = fcwT[(k0 + 1) * 512 + tid];       w1v.y = fcwT[(k0 + 1) * 512 + 256 + tid];
    w0v.z = fcwT[(k0 + 2) * 512 + tid];       w1v.z = fcwT[(k0 + 2) * 512 + 256 + tid];
    w0v.w = fcwT[(k0 + 3) * 512 + tid];       w1v.w = fcwT[(k0 + 3) * 512 + 256 + tid];
    float4 hv[16];
#pragma unroll
    for (int tt = 0; tt < 16; ++tt) hv[tt] = *(const float4*)&smem[tt * 1024 + k0];
#pragma unroll
    for (int tt = 0; tt < 16; ++tt) {
      acc0[tt] += dot4f(w0v, hv[tt]);
      acc1[tt] += dot4f(w1v, hv[tt]);
    }
  }
  float bb0 = fcb[tid], bb1 = fcb[tid + 256];
  __syncthreads();  // done reading h1 tile; alias smem as logits [16][512]
#pragma unroll
  for (int tt = 0; tt < 16; ++tt) {
    smem[tt * 512 + tid] = acc0[tt] + bb0;
    smem[tt * 512 + 256 + tid] = acc1[tt] + bb1;
  }
  __syncthreads();

  const int wv = tid >> 6, l = tid & 63;
  for (int r = 0; r < 4; ++r) {
    int tt = wv * 4 + r;
    float v[8];
    float mx = -3.4e38f;
#pragma unroll
    for (int m = 0; m < 8; ++m) { v[m] = smem[tt * 512 + m * 64 + l]; mx = fmaxf(mx, v[m]); }
#pragma unroll
    for (int s = 1; s < 64; s <<= 1) mx = fmaxf(mx, __shfl_xor(mx, s, 64));
    float sum = 0.f;
#pragma unroll
    for (int m = 0; m < 8; ++m) { v[m] = expf(v[m] - mx); sum += v[m]; }
#pragma unroll
    for (int s = 1; s < 64; s <<= 1) sum += __shfl_xor(sum, s, 64);
    float inv = 1.0f / sum;
#pragma unroll
    for (int m = 0; m < 8; ++m) out[(size_t)(t0 + tt) * 512 + m * 64 + l] = v[m] * inv;
  }
}

extern "C" void kernel_launch(void* const* d_in, const int* in_sizes, int n_in,
                              void* d_out, int out_size, void* d_ws, size_t ws_size,
                              hipStream_t stream) {
  const float* x    = (const float*)d_in[0];
  const float* Wih0 = (const float*)d_in[1];
  const float* Whh0 = (const float*)d_in[2];
  const float* bih0 = (const float*)d_in[3];
  const float* bhh0 = (const float*)d_in[4];
  const float* Wih1 = (const float*)d_in[5];
  const float* Whh1 = (const float*)d_in[6];
  const float* bih1 = (const float*)d_in[7];
  const float* bhh1 = (const float*)d_in[8];
  const float* h0in = (const float*)d_in[9];
  const float* c0in = (const float*)d_in[10];
  const float* fcw  = (const float*)d_in[11];
  const float* fcb  = (const float*)d_in[12];
  float* out = (float*)d_out;

  // workspace: h0buf (B slots) | h1buf (B+1 slots) | fcwT  -> ~66 MB
  u64* h0buf = (u64*)d_ws;
  u64* h1buf = h0buf + (size_t)LSTM_B * 1024;
  float* fcwT = (float*)(h1buf + (size_t)(LSTM_B + 1) * 1024);

  hipLaunchKernelGGL(k_transpose, dim3((512 * 1024) / 256), dim3(256), 0, stream, fcw, fcwT);
  hipLaunchKernelGGL(k_recur, dim3(256), dim3(1024), 0, stream,
                     x, Whh0, Wih0, bih0, bhh0, Wih1, Whh1, bih1, bhh1,
                     h0in, c0in, h0buf, h1buf);
  hipLaunchKernelGGL(k_fc, dim3(LSTM_B / 16), dim3(256), 0, stream, h1buf, fcwT, fcb, out);
}